// Round 12
// baseline (321.025 us; speedup 1.0000x reference)
//
#include <hip/hip_runtime.h>

// Math (verified): softmax over a size-1 axis == 1, so
//   out = relu(x @ (gamma*W3 + W4)^T),  x:(B,20), fused M:(200,20)
// Memory floor: 210 MB out write + 21 MB x read => ~34-37 us.
//
// Evidence ladder:
//  v9 diag: nt stores, distance 2 -> 48 us/pass, 3.9 TB/s, WRITE exact.
//  v10: distance 4 + launch_bounds(256,5) -> SPILLED (VGPR 48, 3.3 GB scratch).
//  v11: distance 4 + PLAIN stores -> WRITE 315 MB (1.54x amplification: 800 B
//       segments are not 128 B-aligned; L2 RFO + whole-line writeback) at
//       2.5 TB/s -> 139.8 us. Plain stores falsified; structure (84 VGPR,
//       no spill, 4 accs, 2 x-buffers, 256 rows/block) proven clean.
//
// v12 = v11 with the 4-store burst made NONTEMPORAL (exact-byte retire, no
// RFO, no amplification). Single-variable change: tests store-MLP distance 4
// with the correct store type. Model: 4 in-flight nt stores/wave x ~8
// waves/CU ~ 7.9 TB/s potential -> main loop should hit the ~6.3 TB/s wall.

#define BATCH          262144
#define DICT           20
#define COLS           200                        // NUM_HEADS * DICT
#define NTHREADS       256                        // 4 waves
#define ROWS_PER_BLOCK 256
#define ROWS_PER_WAVE  64
#define NBLOCKS        (BATCH / ROWS_PER_BLOCK)   // 1024

typedef float f32x4 __attribute__((ext_vector_type(4)));

__global__ __launch_bounds__(NTHREADS, 3)
void attn_v12_kernel(const float* __restrict__ x,
                     const float* __restrict__ W3,
                     const float* __restrict__ W4,
                     const float* __restrict__ gamma,
                     float* __restrict__ out)
{
    __shared__ f32x4 ldsX[ROWS_PER_BLOCK * 5];   // 20 KB x tile

    const int t = threadIdx.x;

    // Stage x tile (read once chip-wide -> nt loads).
    const f32x4* xg = (const f32x4*)(x + (size_t)blockIdx.x * ROWS_PER_BLOCK * DICT);
    for (int i = t; i < ROWS_PER_BLOCK * 5; i += NTHREADS)   // 1280 f4, 5 iters
        ldsX[i] = __builtin_nontemporal_load(&xg[i]);
    __syncthreads();

    const int lane = t & 63;
    const int wv   = t >> 6;          // wave = row group (wave-uniform rows)
    if (lane >= 50) return;           // after the only barrier -> legal

    const float g   = gamma[0];
    const int   cf4 = lane;           // float4-column strip in [0,50)

    // Fused M = g*W3 + W4 for this thread's 4 columns, from global
    // (16 KB, L2-resident). 80 VGPRs, amortized over 64 rows.
    f32x4 m[4][5];
#pragma unroll
    for (int c = 0; c < 4; ++c) {
        const f32x4* a = (const f32x4*)(W3 + (4 * cf4 + c) * DICT);
        const f32x4* b = (const f32x4*)(W4 + (4 * cf4 + c) * DICT);
#pragma unroll
        for (int k = 0; k < 5; ++k) {
            f32x4 p = a[k], q = b[k], r;
            r.x = fmaf(g, p.x, q.x); r.y = fmaf(g, p.y, q.y);
            r.z = fmaf(g, p.z, q.z); r.w = fmaf(g, p.w, q.w);
            m[c][k] = r;
        }
    }

    const int row0 = blockIdx.x * ROWS_PER_BLOCK + wv * ROWS_PER_WAVE;
    const f32x4* xl = &ldsX[wv * ROWS_PER_WAVE * 5];   // wave-uniform base
    f32x4* op = (f32x4*)(out + (size_t)row0 * COLS) + cf4;  // 50 f4/row

#define DOT4(ACC, XP)                                          \
    {                                                          \
        float* ap_ = (float*)&(ACC);                           \
        _Pragma("unroll")                                      \
        for (int c = 0; c < 4; ++c) {                          \
            float p0 = 0.f, p1 = 0.f;                          \
            _Pragma("unroll")                                  \
            for (int k = 0; k < 5; ++k) {                      \
                p0 = fmaf(m[c][k].x, (XP)[k].x, p0);           \
                p1 = fmaf(m[c][k].y, (XP)[k].y, p1);           \
                p0 = fmaf(m[c][k].z, (XP)[k].z, p0);           \
                p1 = fmaf(m[c][k].w, (XP)[k].w, p1);           \
            }                                                  \
            ap_[c] = fmaxf(p0 + p1, 0.f);                      \
        }                                                      \
    }

    // 4-row body, two live x buffers (xv/xn ping-pong; compiler folds them,
    // 84 VGPR proven in v11). Store burst: 4 independent NONTEMPORAL stores
    // -> exact-byte retire, reuse distance 4 -> 4 outstanding per wave.
    f32x4 xv[5], xn[5];
#pragma unroll
    for (int k = 0; k < 5; ++k) xv[k] = xl[k];       // row 0

    for (int r = 0; r < ROWS_PER_WAVE; r += 4) {
        f32x4 a0, a1, a2, a3;

#pragma unroll
        for (int k = 0; k < 5; ++k) xn[k] = xl[(r + 1) * 5 + k];
        DOT4(a0, xv)                                  // row r

#pragma unroll
        for (int k = 0; k < 5; ++k) xv[k] = xl[(r + 2) * 5 + k];
        DOT4(a1, xn)                                  // row r+1

#pragma unroll
        for (int k = 0; k < 5; ++k) xn[k] = xl[(r + 3) * 5 + k];
        DOT4(a2, xv)                                  // row r+2

        if (r + 4 < ROWS_PER_WAVE) {
#pragma unroll
            for (int k = 0; k < 5; ++k) xv[k] = xl[(r + 4) * 5 + k];
        }
        DOT4(a3, xn)                                  // row r+3

        __builtin_nontemporal_store(a0, &op[(size_t)(r + 0) * 50]);
        __builtin_nontemporal_store(a1, &op[(size_t)(r + 1) * 50]);
        __builtin_nontemporal_store(a2, &op[(size_t)(r + 2) * 50]);
        __builtin_nontemporal_store(a3, &op[(size_t)(r + 3) * 50]);
    }
#undef DOT4
}

extern "C" void kernel_launch(void* const* d_in, const int* in_sizes, int n_in,
                              void* d_out, int out_size, void* d_ws, size_t ws_size,
                              hipStream_t stream) {
    const float* x     = (const float*)d_in[0];
    // d_in[1] = W1, d_in[2] = W2 : mathematically unused (softmax over size-1 axis)
    const float* W3    = (const float*)d_in[3];
    const float* W4    = (const float*)d_in[4];
    const float* gamma = (const float*)d_in[5];
    float* out = (float*)d_out;

    attn_v12_kernel<<<NBLOCKS, NTHREADS, 0, stream>>>(x, W3, W4, gamma, out);
}

// Round 13
// 247.749 us; speedup vs baseline: 1.2958x; 1.2958x over previous
//
#include <hip/hip_runtime.h>

// Math (verified): softmax over a size-1 axis == 1, so
//   out = relu(x @ (gamma*W3 + W4)^T),  x:(B,20), fused M:(200,20)
// Memory floor: 210 MB out write + 21 MB x read => ~34-37 us.
//
// Evidence ladder:
//  v6 (128 rows, nt, 2 accs, store-after-DOT4): kernel ~70 us. BEST.
//  v9 = v6 x3: main loop 48 us/pass, 3.9 TB/s, WRITE exact, conflicts 0.
//  v10 (bound 5): spilled. v11 (256 rows, plain, bottom-burst): 139.8 us,
//  WRITE 1.54x. v12 (256 rows, nt, bottom-burst): 141.7 us, WRITE 1.22x.
//  v11 ~= v12 despite opposite store types => the bottom-burst structure
//  itself serialized: all 4 stores issue at loop bottom, next iteration
//  immediately reuses a0 -> vmcnt gate ~0 FMAs after issue -> zero
//  compute/store overlap (VALUBusy 20%). v6 overlapped ~160 FMA-cy/store.
//
// v13 = v6 exactly (128 rows/block, 2048 blocks, nt stores) widened from
// 2 to 4 rotating accumulators with stores ISSUED RIGHT AFTER each DOT4:
// each store gets ~3 DOT4 blocks (~500 cy) of overlap before its register
// reuse gate, AND up to 4 stores are in flight. Single-variable change
// from the proven v6 base.

#define BATCH          262144
#define DICT           20
#define COLS           200                        // NUM_HEADS * DICT
#define NTHREADS       256                        // 4 waves
#define ROWS_PER_BLOCK 128
#define ROWS_PER_WAVE  32
#define NBLOCKS        (BATCH / ROWS_PER_BLOCK)   // 2048

typedef float f32x4 __attribute__((ext_vector_type(4)));

__global__ __launch_bounds__(NTHREADS, 3)
void attn_v13_kernel(const float* __restrict__ x,
                     const float* __restrict__ W3,
                     const float* __restrict__ W4,
                     const float* __restrict__ gamma,
                     float* __restrict__ out)
{
    __shared__ f32x4 ldsX[ROWS_PER_BLOCK * 5];   // 10 KB x tile

    const int t = threadIdx.x;

    // Stage x tile (read once chip-wide -> nt loads).
    const f32x4* xg = (const f32x4*)(x + (size_t)blockIdx.x * ROWS_PER_BLOCK * DICT);
    for (int i = t; i < ROWS_PER_BLOCK * 5; i += NTHREADS)   // 640 f4, 3 iters
        ldsX[i] = __builtin_nontemporal_load(&xg[i]);
    __syncthreads();

    const int lane = t & 63;
    const int wv   = t >> 6;          // wave = row group (wave-uniform rows)
    if (lane >= 50) return;           // after the only barrier -> legal

    const float g   = gamma[0];
    const int   cf4 = lane;           // float4-column strip in [0,50)

    // Fused M = g*W3 + W4 for this thread's 4 columns, from global
    // (16 KB, L2-resident). 80 VGPRs, amortized over 32 rows.
    f32x4 m[4][5];
#pragma unroll
    for (int c = 0; c < 4; ++c) {
        const f32x4* a = (const f32x4*)(W3 + (4 * cf4 + c) * DICT);
        const f32x4* b = (const f32x4*)(W4 + (4 * cf4 + c) * DICT);
#pragma unroll
        for (int k = 0; k < 5; ++k) {
            f32x4 p = a[k], q = b[k], r;
            r.x = fmaf(g, p.x, q.x); r.y = fmaf(g, p.y, q.y);
            r.z = fmaf(g, p.z, q.z); r.w = fmaf(g, p.w, q.w);
            m[c][k] = r;
        }
    }

    const int row0 = blockIdx.x * ROWS_PER_BLOCK + wv * ROWS_PER_WAVE;
    const f32x4* xl = &ldsX[wv * ROWS_PER_WAVE * 5];   // wave-uniform base
    f32x4* op = (f32x4*)(out + (size_t)row0 * COLS) + cf4;  // 50 f4/row

#define DOT4(ACC, XP)                                          \
    {                                                          \
        float* ap_ = (float*)&(ACC);                           \
        _Pragma("unroll")                                      \
        for (int c = 0; c < 4; ++c) {                          \
            float p0 = 0.f, p1 = 0.f;                          \
            _Pragma("unroll")                                  \
            for (int k = 0; k < 5; ++k) {                      \
                p0 = fmaf(m[c][k].x, (XP)[k].x, p0);           \
                p1 = fmaf(m[c][k].y, (XP)[k].y, p1);           \
                p0 = fmaf(m[c][k].z, (XP)[k].z, p0);           \
                p1 = fmaf(m[c][k].w, (XP)[k].w, p1);           \
            }                                                  \
            ap_[c] = fmaxf(p0 + p1, 0.f);                      \
        }                                                      \
    }

    // 4-row body, v6 ordering (store right after each DOT4), 4 rotating
    // accs: each acc's register-reuse gate sits 3 DOT4 blocks (~500 cy)
    // after its store issues; up to 4 nt stores in flight per wave.
    // Two live x buffers only (xv/xn ping-pong; 84 VGPR proven).
    f32x4 xv[5], xn[5];
    f32x4 a0, a1, a2, a3;
#pragma unroll
    for (int k = 0; k < 5; ++k) xv[k] = xl[k];       // row 0

    for (int r = 0; r < ROWS_PER_WAVE; r += 4) {
#pragma unroll
        for (int k = 0; k < 5; ++k) xn[k] = xl[(r + 1) * 5 + k];
        DOT4(a0, xv)                                  // row r
        __builtin_nontemporal_store(a0, &op[(size_t)(r + 0) * 50]);

#pragma unroll
        for (int k = 0; k < 5; ++k) xv[k] = xl[(r + 2) * 5 + k];
        DOT4(a1, xn)                                  // row r+1
        __builtin_nontemporal_store(a1, &op[(size_t)(r + 1) * 50]);

#pragma unroll
        for (int k = 0; k < 5; ++k) xn[k] = xl[(r + 3) * 5 + k];
        DOT4(a2, xv)                                  // row r+2
        __builtin_nontemporal_store(a2, &op[(size_t)(r + 2) * 50]);

        if (r + 4 < ROWS_PER_WAVE) {
#pragma unroll
            for (int k = 0; k < 5; ++k) xv[k] = xl[(r + 4) * 5 + k];
        }
        DOT4(a3, xn)                                  // row r+3
        __builtin_nontemporal_store(a3, &op[(size_t)(r + 3) * 50]);
    }
#undef DOT4
}

extern "C" void kernel_launch(void* const* d_in, const int* in_sizes, int n_in,
                              void* d_out, int out_size, void* d_ws, size_t ws_size,
                              hipStream_t stream) {
    const float* x     = (const float*)d_in[0];
    // d_in[1] = W1, d_in[2] = W2 : mathematically unused (softmax over size-1 axis)
    const float* W3    = (const float*)d_in[3];
    const float* W4    = (const float*)d_in[4];
    const float* gamma = (const float*)d_in[5];
    float* out = (float*)d_out;

    attn_v13_kernel<<<NBLOCKS, NTHREADS, 0, stream>>>(x, W3, W4, gamma, out);
}

// Round 14
// 243.528 us; speedup vs baseline: 1.3182x; 1.0173x over previous
//
#include <hip/hip_runtime.h>

// Math (verified): softmax over a size-1 axis == 1, so
//   out = relu(x @ (gamma*W3 + W4)^T),  x:(B,20), fused M:(200,20)
// Memory floor: 210 MB out write + 21 MB x read => ~34-37 us.
//
// Store-path evidence matrix (all measured on-chip):
//   plain + aligned full lines   : 6.5-6.7 TB/s  (harness fills, FETCH~0)
//   plain + misaligned 800B segs : 2.5 TB/s, 1.54x write amplification (v11)
//   nt    + misaligned 800B segs : 3.9 TB/s, exact bytes (v9/v6/v13;
//                                  invariant to MLP depth 2/4 and overlap)
// v14 buys the first row: per 32-row chunk, accs -> LDS outbuf
// (ds_write_b128, contiguous, lgkm only), barrier, then a fill-style
// LINEAR copy: 256 threads x f4, each wave-instruction = 1024 B fully
// covering aligned 128 B lines -> plain stores, no RFO, no amplification.
// LDS round-trip costs ~6 us chip-wide at 69 TB/s. Target main loop:
// max(32 us stores @6.5, 19 us VALU + 6 us LDS) ~ 34-38 us (was 48).
// Discriminating counter: WRITE_SIZE must be 204800 KB exact with PLAIN
// stores (v11's was 315 MB).

#define BATCH          262144
#define DICT           20
#define COLS           200                        // NUM_HEADS * DICT
#define NTHREADS       256                        // 4 waves
#define ROWS_PER_BLOCK 128
#define CHUNK_ROWS     32
#define NCHUNKS        (ROWS_PER_BLOCK / CHUNK_ROWS)   // 4
#define NBLOCKS        (BATCH / ROWS_PER_BLOCK)        // 2048

typedef float f32x4 __attribute__((ext_vector_type(4)));

__global__ __launch_bounds__(NTHREADS, 3)
void attn_v14_kernel(const float* __restrict__ x,
                     const float* __restrict__ W3,
                     const float* __restrict__ W4,
                     const float* __restrict__ gamma,
                     float* __restrict__ out)
{
    __shared__ f32x4 ldsX[ROWS_PER_BLOCK * 5];    // 10 KB x tile
    __shared__ f32x4 outb[CHUNK_ROWS * 50];       // 25.6 KB out chunk

    const int t = threadIdx.x;

    // Stage x tile (read once chip-wide -> nt loads).
    const f32x4* xg = (const f32x4*)(x + (size_t)blockIdx.x * ROWS_PER_BLOCK * DICT);
    for (int i = t; i < ROWS_PER_BLOCK * 5; i += NTHREADS)   // 640 f4
        ldsX[i] = __builtin_nontemporal_load(&xg[i]);
    __syncthreads();

    const int lane = t & 63;
    const int wv   = t >> 6;          // wave = 8-row slice within each chunk
    const float g  = gamma[0];
    const int  cf4 = lane;            // float4-column strip in [0,50)

    // Fused M = g*W3 + W4 for this thread's 4 columns, from global
    // (16 KB, L2-resident). 80 VGPRs. Lanes >= 50 idle in compute but MUST
    // stay alive for barriers + the copy phase (no early return).
    f32x4 m[4][5];
    if (lane < 50) {
#pragma unroll
        for (int c = 0; c < 4; ++c) {
            const f32x4* a = (const f32x4*)(W3 + (4 * cf4 + c) * DICT);
            const f32x4* b = (const f32x4*)(W4 + (4 * cf4 + c) * DICT);
#pragma unroll
            for (int k = 0; k < 5; ++k) {
                f32x4 p = a[k], q = b[k], r;
                r.x = fmaf(g, p.x, q.x); r.y = fmaf(g, p.y, q.y);
                r.z = fmaf(g, p.z, q.z); r.w = fmaf(g, p.w, q.w);
                m[c][k] = r;
            }
        }
    }

#define DOT4(ACC, XP)                                          \
    {                                                          \
        float* ap_ = (float*)&(ACC);                           \
        _Pragma("unroll")                                      \
        for (int c = 0; c < 4; ++c) {                          \
            float p0 = 0.f, p1 = 0.f;                          \
            _Pragma("unroll")                                  \
            for (int k = 0; k < 5; ++k) {                      \
                p0 = fmaf(m[c][k].x, (XP)[k].x, p0);           \
                p1 = fmaf(m[c][k].y, (XP)[k].y, p1);           \
                p0 = fmaf(m[c][k].z, (XP)[k].z, p0);           \
                p1 = fmaf(m[c][k].w, (XP)[k].w, p1);           \
            }                                                  \
            ap_[c] = fmaxf(p0 + p1, 0.f);                      \
        }                                                      \
    }

    // Block's output region: 128 rows * 800 B = 102400 B, 128 B-aligned.
    f32x4* dstbase = (f32x4*)(out + (size_t)blockIdx.x * ROWS_PER_BLOCK * COLS);

    for (int ch = 0; ch < NCHUNKS; ++ch) {
        // ---- compute phase: wave wv computes rows ch*32 + wv*8 .. +7 ----
        if (lane < 50) {
            const f32x4* xl = &ldsX[(ch * CHUNK_ROWS + wv * 8) * 5];
            f32x4* ob = &outb[(size_t)(wv * 8) * 50 + cf4];
#pragma unroll
            for (int r = 0; r < 8; ++r) {
                f32x4 xv[5];
#pragma unroll
                for (int k = 0; k < 5; ++k) xv[k] = xl[r * 5 + k];
                f32x4 acc;
                DOT4(acc, xv)
                ob[(size_t)r * 50] = acc;    // ds_write_b128, contiguous
            }
        }
        __syncthreads();

        // ---- copy phase: fill-style linear copy, plain stores ----
        // 1600 f4 per chunk; wave-instruction = 64 lanes * 16 B = 1024 B,
        // aligned -> every 128 B line fully covered -> no RFO.
        f32x4* dst = dstbase + (size_t)ch * (CHUNK_ROWS * 50);
#pragma unroll
        for (int j = 0; j < 6; ++j)                  // 6*256 = 1536
            dst[t + NTHREADS * j] = outb[t + NTHREADS * j];
        if (t < CHUNK_ROWS * 50 - 6 * NTHREADS)      // tail 64 (wave 0)
            dst[6 * NTHREADS + t] = outb[6 * NTHREADS + t];
        __syncthreads();                             // outb reused next chunk
    }
#undef DOT4
}

extern "C" void kernel_launch(void* const* d_in, const int* in_sizes, int n_in,
                              void* d_out, int out_size, void* d_ws, size_t ws_size,
                              hipStream_t stream) {
    const float* x     = (const float*)d_in[0];
    // d_in[1] = W1, d_in[2] = W2 : mathematically unused (softmax over size-1 axis)
    const float* W3    = (const float*)d_in[3];
    const float* W4    = (const float*)d_in[4];
    const float* gamma = (const float*)d_in[5];
    float* out = (float*)d_out;

    attn_v14_kernel<<<NBLOCKS, NTHREADS, 0, stream>>>(x, W3, W4, gamma, out);
}